// Round 1
// baseline (163.476 us; speedup 1.0000x reference)
//
#include <hip/hip_runtime.h>

#define N_IMG   1024
#define N_VIEWS 90
#define CENTER  512
#define TILE    64
#define NTX     (N_IMG / TILE)      // 16 x-tiles
#define NTHREADS 512
#define NWAVES   8
#define YPT      (TILE / NWAVES)    // 8 samples per thread per job
#define TILE_WORDS 9216             // >= 93*97+95 (raw-bbox + drift pad); 36.9 KB per buffer

typedef float v2f __attribute__((ext_vector_type(2)));

// x_in =  ca*X + sa*Y + cx,  cx = CENTER*(1 - ca - sa)
// y_in = -sa*X + ca*Y + cy,  cy = CENTER*(1 - ca + sa)
// Fixed fmaf chain: corner extremes == sample extremes (monotone per variable).
__device__ __forceinline__ void map_coords(float ca, float sa, float cx, float cy,
                                           float Xf, float Yf,
                                           float& x_in, float& y_in) {
    const float fx0 = fmaf(ca, Xf, cx);
    const float fy0 = fmaf(-sa, Xf, cy);
    x_in = fmaf(sa, Yf, fx0);
    y_in = fmaf(ca, Yf, fy0);
}

__device__ __forceinline__ void gload_lds4(const float* g, float* l) {
    __builtin_amdgcn_global_load_lds((const __attribute__((address_space(1))) void*)g,
                                     (__attribute__((address_space(3))) void*)l, 4, 0, 0);
}
__device__ __forceinline__ void gload_lds16(const float* g, float* l) {
    __builtin_amdgcn_global_load_lds((const __attribute__((address_space(1))) void*)g,
                                     (__attribute__((address_space(3))) void*)l, 16, 0, 0);
}

// Fast bilinear sampler — unchanged numerics. Pairs on float2 ext-vectors so
// mul/add/fma issue packed; floor/cvt stay scalar. Buffer padded so a +-1
// floor overshoot stays in-bounds (weight ~0 there).
template<int STRIDE>
__device__ __forceinline__ float sample_tile(const float* __restrict__ tile,
                                             float sa, float ca,
                                             float x_in, float y_in, float basef) {
    const float Sf = (float)STRIDE;
    v2f x2 = {x_in, x_in + sa};
    v2f y2 = {y_in, y_in + ca};
    const v2f dx2 = {2.0f * sa, 2.0f * sa};
    const v2f dy2 = {2.0f * ca, 2.0f * ca};
    const v2f S2  = {Sf, Sf};
    const v2f b2  = {basef, basef};
    v2f acc2 = {0.0f, 0.0f};
    #pragma unroll
    for (int p = 0; p < YPT / 2; ++p) {
        v2f x0f = {floorf(x2.x), floorf(x2.y)};
        v2f y0f = {floorf(y2.x), floorf(y2.y)};
        const v2f wx = x2 - x0f;
        const v2f wy = y2 - y0f;
        const v2f lif = y0f * S2 + x0f + b2;     // exact < 2^23
        const int li0 = (int)lif.x;
        const int li1 = (int)lif.y;
        const v2f t00 = {tile[li0],              tile[li1]};              // ds_read2
        const v2f t01 = {tile[li0 + 1],          tile[li1 + 1]};
        const v2f t10 = {tile[li0 + STRIDE],     tile[li1 + STRIDE]};     // ds_read2
        const v2f t11 = {tile[li0 + STRIDE + 1], tile[li1 + STRIDE + 1]};
        const v2f top = (t01 - t00) * wx + t00;
        const v2f bot = (t11 - t10) * wx + t10;
        acc2 += (bot - top) * wy + top;
        x2 += dx2; y2 += dy2;
    }
    return acc2.x + acc2.y;
}

struct JobP { int win, dB, iy0, nrows, ry0, fl; };

// One block = one (angle, x-tile) group; iterates the 16 y-tiles with a
// double-buffered LDS pipeline (stage ty+1 while sampling ty), accumulating
// the column sums in registers; single block-reduce + store at the end.
__global__ __launch_bounds__(NTHREADS, 4) void radon_fused(const float* __restrict__ img,
                                                           const float* __restrict__ theta,
                                                           float* __restrict__ out) {
    __shared__ float tile[2][TILE_WORDS];    // 73.7 KB -> 2 blocks/CU

    const int bx  = blockIdx.x;
    const int a   = bx >> 4;                 // / NTX
    const int tx  = bx & (NTX - 1);
    const int X0  = tx * TILE;
    const int tid  = threadIdx.x;
    const int lane = tid & 63;
    const int wv   = tid >> 6;               // 0..7

    // ---- block-uniform per-angle params (every thread; cheap, no barrier) ----
    const float ang = theta[a] * 0.017453292519943295f;
    float sa, ca;
    __sincosf(ang, &sa, &ca);
    const float cx = (float)CENTER * (1.0f - ca - sa);
    const float cy = (float)CENTER * (1.0f - ca + sa);
    const int path = (fabsf(ca) > 0.7072f) ? 0 : ((ca > 0.0f) ? 1 : 2);
    const int S = (path == 0) ? 96 : ((path == 1) ? 95 : 97);

    // ---- per-lane job params: lane (mod 16) computes window for ty = lane&15 ----
    const int tyl = lane & 15;
    const float Ybase = (float)(tyl * TILE);
    float x00, y00, x01, y01, x10, y10, x11, y11;
    map_coords(ca, sa, cx, cy, (float)X0,        Ybase,        x00, y00);
    map_coords(ca, sa, cx, cy, (float)(X0 + 63), Ybase,        x01, y01);
    map_coords(ca, sa, cx, cy, (float)X0,        Ybase + 63.f, x10, y10);
    map_coords(ca, sa, cx, cy, (float)(X0 + 63), Ybase + 63.f, x11, y11);
    const float xmin = fminf(fminf(x00, x01), fminf(x10, x11));
    const float xmax = fmaxf(fmaxf(x00, x01), fmaxf(x10, x11));
    const float ymin = fminf(fminf(y00, y01), fminf(y10, y11));
    const float ymax = fmaxf(fmaxf(y00, y01), fmaxf(y10, y11));

    const int ix0_raw = (int)floorf(xmin);
    const int ix1_raw = (int)floorf(xmax) + 1;   // max x-tap; span <= 91
    const int iy0_raw = (int)floorf(ymin);
    const int iy1_raw = (int)floorf(ymax) + 1;   // max y-tap; span <= 91

    const bool empty = (ix1_raw < 0) || (ix0_raw > N_IMG - 1) ||
                       (iy1_raw < 0) || (iy0_raw > N_IMG - 1);
    const bool interior = (ix0_raw >= 0) && (ix1_raw <= N_IMG - 1) &&
                          (iy0_raw >= 0) && (iy1_raw <= N_IMG - 1);

    int winl, dBl = 0, ry0l = 0, nrl = 0, iy0l = iy0_raw;
    if (interior) {
        if (path == 0) {
            winl = min(ix0_raw & ~3, N_IMG - 96);          // 96-px in-image window
        } else {
            winl = min(ix0_raw, N_IMG - 64);               // dual 64-px segments
            dBl  = max(winl, ix1_raw - 63) - winl;         // 0..28
        }
        nrl = iy1_raw - iy0_raw + 1;                       // <= 92 staged rows
    } else {
        winl = ix0_raw & ~3;                               // raw 4-aligned window
        ry0l = max(0, iy0_raw);                            // in-image rows to stage
        nrl  = min(N_IMG - 1, iy1_raw) - ry0l + 1;
    }
    const int fll = empty ? 1 : (interior ? 2 : 0);

    // broadcast of job ty's params (6 shuffles, ~free vs redundant recompute)
    auto fetch = [&](int ty) -> JobP {
        JobP p;
        p.win   = __shfl(winl, ty);
        p.dB    = __shfl(dBl,  ty);
        p.iy0   = __shfl(iy0l, ty);
        p.nrows = __shfl(nrl,  ty);
        p.ry0   = __shfl(ry0l, ty);
        p.fl    = __shfl(fll,  ty);
        return p;
    };

    auto stage = [&](const JobP& p, float* buf) {
        if (p.fl & 1) return;                   // fully outside image
        if (p.fl & 2) {
            // interior: async DMA, no VGPR round-trip
            if (path == 0) {
                const int D = p.nrows * 96;
                for (int o = wv * 256; o < D; o += NWAVES * 256) {
                    const int d = o + 4 * lane;
                    const int r = (unsigned)d / 96u;
                    const int c = d - r * 96;
                    const int gr = min(p.iy0 + r, N_IMG - 1);   // overshoot clamp
                    gload_lds16(img + (size_t)gr * N_IMG + p.win + c, buf + o);
                }
            } else {
                const float* g = img + (size_t)(p.iy0 + wv) * N_IMG + p.win + lane;
                float* l = buf + wv * S;
                for (int r = wv; r < p.nrows; r += NWAVES) {
                    gload_lds4(g, l);
                    if (p.dB > 0) gload_lds4(g + p.dB, l + p.dB);
                    g += NWAVES * N_IMG;
                    l += NWAVES * S;
                }
            }
        } else {
            // border: zero-fill then guarded float4 copy of in-image part
            for (int o4 = tid; o4 < TILE_WORDS / 4; o4 += NTHREADS)
                *(float4*)(buf + 4 * o4) = make_float4(0.f, 0.f, 0.f, 0.f);
            __syncthreads();
            const int cx0 = max(0, p.win);                  // 4-aligned
            const int cxe = min(N_IMG - 1, p.win + 94);     // last needed col
            const int wIn = cxe - cx0 + 1;                  // 1..95
            const int n4  = wIn >> 2;
            const int items = p.nrows * 24;
            for (int idx = tid; idx < items; idx += NTHREADS) {
                const int r  = (unsigned)idx / 24u;
                const int c4 = idx - r * 24;
                const int gy = p.ry0 + r;
                float* dst = buf + (gy - p.iy0) * S + (cx0 - p.win) + 4 * c4;
                const float* src = img + (size_t)gy * N_IMG + cx0 + 4 * c4;
                if (c4 < n4) {
                    *(float4*)dst = *(const float4*)src;
                } else if (c4 == n4) {
                    for (int j = 0; j < (wIn & 3); ++j) dst[j] = src[j];
                }
            }
        }
    };

    // ---- per-thread sample-line constants ----
    const float Xf  = (float)(X0 + lane);
    const float fx0 = fmaf(ca, Xf, cx);
    const float fy0 = fmaf(-sa, Xf, cy);
    float acc = 0.0f;

    // ---- prologue: stage job 0, full drain once ----
    JobP pc = fetch(0);
    stage(pc, tile[0]);
    __syncthreads();

    // ---- pipelined job loop: stage ty+1, sample ty, one barrier ----
    for (int ty = 0; ty < 16; ++ty) {
        JobP pn = pc;
        if (ty < 15) {
            pn = fetch(ty + 1);
            stage(pn, tile[(ty + 1) & 1]);      // loads in flight across sample
        }
        if (!(pc.fl & 1)) {
            const float Ybf  = (float)(ty * TILE + wv * YPT);
            const float x_in = fmaf(sa, Ybf, fx0);
            const float y_in = fmaf(ca, Ybf, fy0);
            const float basef = -(float)(pc.iy0 * S + pc.win);
            const float* tl = tile[ty & 1];
            if (path == 0)      acc += sample_tile<96>(tl, sa, ca, x_in, y_in, basef);
            else if (path == 1) acc += sample_tile<95>(tl, sa, ca, x_in, y_in, basef);
            else                acc += sample_tile<97>(tl, sa, ca, x_in, y_in, basef);
        }
        __syncthreads();   // drains own prefetch (issued one sample-phase ago) + swap
        pc = pn;
    }

    // ---- single block reduce at group end; overlay buffer 0 ----
    tile[0][wv * 64 + lane] = acc;
    __syncthreads();
    if (wv == 0) {
        float s = 0.0f;
        #pragma unroll
        for (int w = 0; w < NWAVES; ++w) s += tile[0][w * 64 + lane];
        out[(X0 + lane) * N_VIEWS + a] = s;
    }
}

extern "C" void kernel_launch(void* const* d_in, const int* in_sizes, int n_in,
                              void* d_out, int out_size, void* d_ws, size_t ws_size,
                              hipStream_t stream) {
    const float* img   = (const float*)d_in[0];   // [1024, 1024] f32
    const float* theta = (const float*)d_in[1];   // [90] f32 degrees
    float* out = (float*)d_out;                   // [1024, 90] f32
    (void)d_ws; (void)ws_size;

    radon_fused<<<dim3(N_VIEWS * NTX), NTHREADS, 0, stream>>>(img, theta, out);
}

// Round 2
// 157.110 us; speedup vs baseline: 1.0405x; 1.0405x over previous
//
#include <hip/hip_runtime.h>

#define N_IMG   1024
#define N_VIEWS 90
#define CENTER  512
#define NTHREADS 512
#define NWAVES   8
#define JOBS     16                 // half-jobs per block, each 64 wide x 32 tall
#define JOBH     32                 // y-rows per half-job
#define YPT      (JOBH / NWAVES)    // 4 samples per thread per job
#define BUF_WORDS 5120              // 20 KB/buffer; 2 buffers = 40 KB -> 4 blocks/CU
// stride A (|ca|>=|sa|): cols<=73 -> stride 74, rows<=69 : 69*74=5106 <= 5120
// stride B (|sa|> |ca|): cols<=69 -> stride 70, rows<=73 : 73*70=5110 <= 5120

typedef float v2f __attribute__((ext_vector_type(2)));

// x_in =  ca*X + sa*Y + cx,  cx = CENTER*(1 - ca - sa)
// y_in = -sa*X + ca*Y + cy,  cy = CENTER*(1 - ca + sa)
// Fixed fmaf chain: corner extremes == sample extremes (monotone per variable).
__device__ __forceinline__ void map_coords(float ca, float sa, float cx, float cy,
                                           float Xf, float Yf,
                                           float& x_in, float& y_in) {
    const float fx0 = fmaf(ca, Xf, cx);
    const float fy0 = fmaf(-sa, Xf, cy);
    x_in = fmaf(sa, Yf, fx0);
    y_in = fmaf(ca, Yf, fy0);
}

// global->LDS DMA: global address is PER-LANE, LDS dest is wave-uniform base
// (HW writes base + lane*4). Exec-masked: inactive lanes write nothing.
__device__ __forceinline__ void gload_lds4(const float* g, float* l) {
    __builtin_amdgcn_global_load_lds((const __attribute__((address_space(1))) void*)g,
                                     (__attribute__((address_space(3))) void*)l, 4, 0, 0);
}

// Bilinear sampler, numerics unchanged from the verified kernel. Pairs on
// float2 ext-vectors (packed fp32); incremental coords drift <= ~2e-4 px over
// YPT=4 steps; a +-1 floor overshoot reads a ~0-weight word that lands either
// in the neighbor buffer (finite image data) or LDS-OOB (returns 0) — error
// bounded by ~1e-3, far under the 0.5 tolerance.
template<int STRIDE>
__device__ __forceinline__ float sample_tile(const float* __restrict__ tile,
                                             float sa, float ca,
                                             float x_in, float y_in, float basef) {
    const float Sf = (float)STRIDE;
    v2f x2 = {x_in, x_in + sa};
    v2f y2 = {y_in, y_in + ca};
    const v2f dx2 = {2.0f * sa, 2.0f * sa};
    const v2f dy2 = {2.0f * ca, 2.0f * ca};
    const v2f S2  = {Sf, Sf};
    const v2f b2  = {basef, basef};
    v2f acc2 = {0.0f, 0.0f};
    #pragma unroll
    for (int p = 0; p < YPT / 2; ++p) {
        v2f x0f = {floorf(x2.x), floorf(x2.y)};
        v2f y0f = {floorf(y2.x), floorf(y2.y)};
        const v2f wx = x2 - x0f;
        const v2f wy = y2 - y0f;
        const v2f lif = y0f * S2 + x0f + b2;     // exact < 2^23
        const int li0 = (int)lif.x;
        const int li1 = (int)lif.y;
        const v2f t00 = {tile[li0],              tile[li1]};              // ds_read2
        const v2f t01 = {tile[li0 + 1],          tile[li1 + 1]};
        const v2f t10 = {tile[li0 + STRIDE],     tile[li1 + STRIDE]};     // ds_read2
        const v2f t11 = {tile[li0 + STRIDE + 1], tile[li1 + STRIDE + 1]};
        const v2f top = (t01 - t00) * wx + t00;
        const v2f bot = (t11 - t10) * wx + t10;
        acc2 += (bot - top) * wy + top;
        x2 += dx2; y2 += dy2;
    }
    return acc2.x + acc2.y;
}

// One block = (angle, x-tile, y-half): 16 half-jobs of 64x32, double-buffered
// LDS pipeline (stage j+1 while sampling j), register column-accumulate,
// single reduce + atomicAdd (2 contributions per output cell).
__global__ __launch_bounds__(NTHREADS, 8) void radon_fused(const float* __restrict__ img,
                                                           const float* __restrict__ theta,
                                                           float* __restrict__ out) {
    __shared__ float tile[2][BUF_WORDS];   // 40 KB exactly -> 4 blocks/CU

    const int tx = blockIdx.x;
    const int h  = blockIdx.y;
    const int a  = blockIdx.z;
    const int X0 = tx * 64;
    const int Y0 = h * (JOBS * JOBH);      // 0 or 512
    const int tid  = threadIdx.x;
    const int lane = tid & 63;
    const int wv   = tid >> 6;             // 0..7

    // ---- block-uniform per-angle params ----
    const float ang = theta[a] * 0.017453292519943295f;
    float sa, ca;
    __sincosf(ang, &sa, &ca);
    const float cx = (float)CENTER * (1.0f - ca - sa);
    const float cy = (float)CENTER * (1.0f - ca + sa);
    const bool pathA = (fabsf(ca) >= fabsf(sa));
    const int S = pathA ? 74 : 70;         // LDS row stride (runtime for staging)

    // ---- per-lane job params: lane j (mod 16) owns half-job j ----
    const int jj = lane & (JOBS - 1);
    const float Yb = (float)(Y0 + jj * JOBH);
    float x00, y00, x01, y01, x10, y10, x11, y11;
    map_coords(ca, sa, cx, cy, (float)X0,        Yb,         x00, y00);
    map_coords(ca, sa, cx, cy, (float)(X0 + 63), Yb,         x01, y01);
    map_coords(ca, sa, cx, cy, (float)X0,        Yb + 31.f,  x10, y10);
    map_coords(ca, sa, cx, cy, (float)(X0 + 63), Yb + 31.f,  x11, y11);
    const float xmin = fminf(fminf(x00, x01), fminf(x10, x11));
    const float xmax = fmaxf(fmaxf(x00, x01), fmaxf(x10, x11));
    const float ymin = fminf(fminf(y00, y01), fminf(y10, y11));
    const float ymax = fmaxf(fmaxf(y00, y01), fmaxf(y10, y11));

    const int ix0 = (int)floorf(xmin);
    const int ix1 = (int)floorf(xmax) + 1;   // max x-tap; count <= 73 (A) / 69 (B)
    const int gy0 = (int)floorf(ymin);
    const int gy1 = (int)floorf(ymax) + 1;   // max y-tap; count <= 69 (A) / 73 (B)

    const bool empty = (ix1 < 0) || (ix0 > N_IMG - 1) ||
                       (gy1 < 0) || (gy0 > N_IMG - 1);
    const bool interior = (ix0 >= 0) && (ix1 <= N_IMG - 1) &&
                          (gy0 >= 0) && (gy1 <= N_IMG - 1);

    // dual 64-col segments [win,win+63] U [win+dB,win+dB+63] cover [win, ix1]
    const int winl = interior ? min(ix0, N_IMG - 64) : ix0;
    const int dBl  = max(0, ix1 - 63 - winl);              // <= 9
    const int nrl  = gy1 - gy0 + 1;
    const int iy0l = gy0;
    const int fll  = empty ? 1 : (interior ? 2 : 0);

    // ---- shuffle-broadcast of job j's params ----
    int wn, dn, yn, nn, fn;
    auto fetch = [&](int j) {
        wn = __shfl(winl, j); dn = __shfl(dBl, j);
        yn = __shfl(iy0l, j); nn = __shfl(nrl, j); fn = __shfl(fll, j);
    };

    // ---- barrier-free staging (interior: pure DMA; border: masked DMA + 0s) ----
    auto stage = [&](int win, int dB, int py0, int nrows, int fl, float* buf) {
        if (fl == 1) return;
        if (fl == 2) {
            const float* g = img + (size_t)(py0 + wv) * N_IMG + win + lane;
            float* l = buf + wv * S;                       // wave-uniform LDS base
            for (int r = wv; r < nrows; r += NWAVES) {
                gload_lds4(g, l);
                if (dB > 0) gload_lds4(g + dB, l + dB);
                g += NWAVES * N_IMG;
                l += NWAVES * S;
            }
        } else {
            for (int r = wv; r < nrows; r += NWAVES) {
                const int gy = py0 + r;
                const bool rOK = ((unsigned)gy < (unsigned)N_IMG);
                const int gx = win + lane;
                const float* gp = img + (size_t)gy * N_IMG;
                float* l = buf + r * S;                    // wave-uniform LDS base
                if (rOK && (unsigned)gx < (unsigned)N_IMG) gload_lds4(gp + gx, l);
                else l[lane] = 0.0f;                       // ds_write zero
                if (dB > 0) {
                    const int gx2 = gx + dB;
                    if (rOK && (unsigned)gx2 < (unsigned)N_IMG) gload_lds4(gp + gx2, l + dB);
                    else l[dB + lane] = 0.0f;
                }
            }
        }
    };

    // ---- per-thread sample-line constants ----
    const float Xf  = (float)(X0 + lane);
    const float fx0 = fmaf(ca, Xf, cx);
    const float fy0 = fmaf(-sa, Xf, cy);
    float acc = 0.0f;

    // ---- prologue: stage job 0, drain once ----
    fetch(0);
    int wc = wn, dc = dn, yc = yn, nc = nn, fc = fn;
    stage(wc, dc, yc, nc, fc, tile[0]);
    __syncthreads();

    // ---- pipelined loop: issue stage j+1, sample j, one barrier per job ----
    for (int j = 0; j < JOBS; ++j) {
        if (j < JOBS - 1) {
            fetch(j + 1);
            stage(wn, dn, yn, nn, fn, tile[(j + 1) & 1]);  // in flight across sample
        }
        if (fc != 1) {
            const float Ybf  = (float)(Y0 + j * JOBH + wv * YPT);
            const float x_in = fmaf(sa, Ybf, fx0);
            const float y_in = fmaf(ca, Ybf, fy0);
            const float basef = -(float)(yc * S + wc);
            const float* tl = tile[j & 1];
            acc += pathA ? sample_tile<74>(tl, sa, ca, x_in, y_in, basef)
                         : sample_tile<70>(tl, sa, ca, x_in, y_in, basef);
        }
        __syncthreads();   // drains prefetch issued one sample-phase ago; swap
        wc = wn; dc = dn; yc = yn; nc = nn; fc = fn;
    }

    // ---- block reduce (overlay buffer 0) + atomic merge of the 2 y-halves ----
    tile[0][wv * 64 + lane] = acc;
    __syncthreads();
    if (wv == 0) {
        float s = 0.0f;
        #pragma unroll
        for (int w = 0; w < NWAVES; ++w) s += tile[0][w * 64 + lane];
        atomicAdd(&out[(X0 + lane) * N_VIEWS + a], s);
    }
}

extern "C" void kernel_launch(void* const* d_in, const int* in_sizes, int n_in,
                              void* d_out, int out_size, void* d_ws, size_t ws_size,
                              hipStream_t stream) {
    const float* img   = (const float*)d_in[0];   // [1024, 1024] f32
    const float* theta = (const float*)d_in[1];   // [90] f32 degrees
    float* out = (float*)d_out;                   // [1024, 90] f32
    (void)d_ws; (void)ws_size;

    (void)hipMemsetAsync(d_out, 0, (size_t)out_size * sizeof(float), stream);
    radon_fused<<<dim3(16, 2, N_VIEWS), NTHREADS, 0, stream>>>(img, theta, out);
}

// Round 3
// 139.297 us; speedup vs baseline: 1.1736x; 1.1279x over previous
//
#include <hip/hip_runtime.h>

#define N_IMG   1024
#define N_VIEWS 90
#define CENTER  512
#define TILE    64
#define NTHREADS 512
#define NWAVES   8
#define YPT      (TILE / NWAVES)    // 8 dst rows per thread per job
#define JOBS     4                  // jobs per block: grid.y=4 quarters of 16 y-tiles
#define TILE_WORDS 9216             // >= 93*97+95 (raw-bbox + drift pad); 36.9 KB

typedef float v2f __attribute__((ext_vector_type(2)));

// x_in =  ca*X + sa*Y + cx,  cx = CENTER*(1 - ca - sa)
// y_in = -sa*X + ca*Y + cy,  cy = CENTER*(1 - ca + sa)
// Fixed fmaf chain: corner extremes == sample extremes (monotone per variable).
__device__ __forceinline__ void map_coords(float ca, float sa, float cx, float cy,
                                           float Xf, float Yf,
                                           float& x_in, float& y_in) {
    const float fx0 = fmaf(ca, Xf, cx);
    const float fy0 = fmaf(-sa, Xf, cy);
    x_in = fmaf(sa, Yf, fx0);
    y_in = fmaf(ca, Yf, fy0);
}

__device__ __forceinline__ void gload_lds4(const float* g, float* l) {
    __builtin_amdgcn_global_load_lds((const __attribute__((address_space(1))) void*)g,
                                     (__attribute__((address_space(3))) void*)l, 4, 0, 0);
}
__device__ __forceinline__ void gload_lds16(const float* g, float* l) {
    __builtin_amdgcn_global_load_lds((const __attribute__((address_space(1))) void*)g,
                                     (__attribute__((address_space(3))) void*)l, 16, 0, 0);
}

// Bilinear sampler — identical numerics to the verified round-0 kernel.
// Pairs on float2 ext-vectors (packed fp32); floor/cvt scalar. Incremental
// coords: <=6 packed adds, drift <=4e-4 px; buffer padded so a +-1 floor
// overshoot stays in-bounds (weight ~0 there).
template<int STRIDE>
__device__ __forceinline__ float sample_tile(const float* __restrict__ tile,
                                             float sa, float ca,
                                             float x_in, float y_in, float basef) {
    const float Sf = (float)STRIDE;
    v2f x2 = {x_in, x_in + sa};
    v2f y2 = {y_in, y_in + ca};
    const v2f dx2 = {2.0f * sa, 2.0f * sa};
    const v2f dy2 = {2.0f * ca, 2.0f * ca};
    const v2f S2  = {Sf, Sf};
    const v2f b2  = {basef, basef};
    v2f acc2 = {0.0f, 0.0f};
    #pragma unroll
    for (int p = 0; p < YPT / 2; ++p) {
        v2f x0f = {floorf(x2.x), floorf(x2.y)};
        v2f y0f = {floorf(y2.x), floorf(y2.y)};
        const v2f wx = x2 - x0f;
        const v2f wy = y2 - y0f;
        const v2f lif = y0f * S2 + x0f + b2;     // exact < 2^23
        const int li0 = (int)lif.x;
        const int li1 = (int)lif.y;
        const v2f t00 = {tile[li0],              tile[li1]};              // ds_read2
        const v2f t01 = {tile[li0 + 1],          tile[li1 + 1]};
        const v2f t10 = {tile[li0 + STRIDE],     tile[li1 + STRIDE]};     // ds_read2
        const v2f t11 = {tile[li0 + STRIDE + 1], tile[li1 + STRIDE + 1]};
        const v2f top = (t01 - t00) * wx + t00;
        const v2f bot = (t11 - t10) * wx + t10;
        acc2 += (bot - top) * wy + top;
        x2 += dx2; y2 += dy2;
    }
    return acc2.x + acc2.y;
}

// One block = (angle, x-tile, y-quarter): 4 sequential 64x64 jobs using the
// round-0 staging engine (single 36.9 KB buffer, 4 blocks/CU), register
// column-accumulate across jobs, one reduce + atomicAdd at the end.
__global__ __launch_bounds__(NTHREADS, 8) void radon_fused(const float* __restrict__ img,
                                                           const float* __restrict__ theta,
                                                           float* __restrict__ out) {
    __shared__ float tile[TILE_WORDS];   // 36.9 KB -> 4 blocks/CU, 32 waves

    const int tx = blockIdx.x;
    const int h  = blockIdx.y;           // y-quarter 0..3
    const int a  = blockIdx.z;
    const int X0 = tx * TILE;
    const int Yq = h * (JOBS * TILE);    // 0,256,512,768
    const int tid  = threadIdx.x;
    const int lane = tid & 63;
    const int wv   = tid >> 6;           // 0..7

    // ---- block-uniform per-angle params (every thread; cheap, no barrier) ----
    const float ang = theta[a] * 0.017453292519943295f;
    float sa, ca;
    __sincosf(ang, &sa, &ca);
    const float cx = (float)CENTER * (1.0f - ca - sa);
    const float cy = (float)CENTER * (1.0f - ca + sa);
    const int path = (fabsf(ca) > 0.7072f) ? 0 : ((ca > 0.0f) ? 1 : 2);
    const int S = (path == 0) ? 96 : ((path == 1) ? 95 : 97);

    // ---- per-lane job params: lane (mod 4) owns job jj (round-0 formulas) ----
    const int jj = lane & (JOBS - 1);
    const float Yb = (float)(Yq + jj * TILE);
    float x00, y00, x01, y01, x10, y10, x11, y11;
    map_coords(ca, sa, cx, cy, (float)X0,        Yb,        x00, y00);
    map_coords(ca, sa, cx, cy, (float)(X0 + 63), Yb,        x01, y01);
    map_coords(ca, sa, cx, cy, (float)X0,        Yb + 63.f, x10, y10);
    map_coords(ca, sa, cx, cy, (float)(X0 + 63), Yb + 63.f, x11, y11);
    const float xmin = fminf(fminf(x00, x01), fminf(x10, x11));
    const float xmax = fmaxf(fmaxf(x00, x01), fmaxf(x10, x11));
    const float ymin = fminf(fminf(y00, y01), fminf(y10, y11));
    const float ymax = fmaxf(fmaxf(y00, y01), fmaxf(y10, y11));

    const int ix0_raw = (int)floorf(xmin);
    const int ix1_raw = (int)floorf(xmax) + 1;   // max x-tap; span <= 91
    const int iy0_raw = (int)floorf(ymin);
    const int iy1_raw = (int)floorf(ymax) + 1;   // max y-tap; span <= 91

    const bool empty = (ix1_raw < 0) || (ix0_raw > N_IMG - 1) ||
                       (iy1_raw < 0) || (iy0_raw > N_IMG - 1);
    const bool interior = (ix0_raw >= 0) && (ix1_raw <= N_IMG - 1) &&
                          (iy0_raw >= 0) && (iy1_raw <= N_IMG - 1);

    int winl, dBl = 0, ry0l = 0, nrl = 0;
    const int iy0l = iy0_raw;
    if (interior) {
        if (path == 0) {
            winl = min(ix0_raw & ~3, N_IMG - 96);          // 96-px in-image window
        } else {
            winl = min(ix0_raw, N_IMG - 64);               // dual 64-px segments
            dBl  = max(winl, ix1_raw - 63) - winl;         // 0..28
        }
        nrl = iy1_raw - iy0_raw + 1;                       // <= 92 staged rows
    } else {
        // border: RAW (unclamped) 4-aligned window; zeros pad off-image.
        winl = ix0_raw & ~3;                               // col offset <= 94 < 95
        ry0l = max(0, iy0_raw);                            // in-image rows to stage
        nrl  = min(N_IMG - 1, iy1_raw) - ry0l + 1;
    }
    const int fll = empty ? 1 : (interior ? 2 : 0);

    // ---- per-thread sample-line constants ----
    const float Xf  = (float)(X0 + lane);
    const float fx0 = fmaf(ca, Xf, cx);
    const float fy0 = fmaf(-sa, Xf, cy);
    float accv = 0.0f;

    // ---- sequential jobs: stage -> sync -> sample -> sync (round-0 engine) ----
    for (int j = 0; j < JOBS; ++j) {
        const int win   = __shfl(winl, j);
        const int dB    = __shfl(dBl,  j);
        const int iy0   = __shfl(iy0l, j);
        const int nrows = __shfl(nrl,  j);
        const int ry0   = __shfl(ry0l, j);
        const int fl    = __shfl(fll,  j);
        if (fl == 1) continue;                   // block-uniform: skip empty job

        if (fl & 2) {
            // ---- interior staging: async DMA (no VGPR round-trip) ----
            if (path == 0) {
                const int D = nrows * 96;
                for (int o = wv * 256; o < D; o += NWAVES * 256) {
                    const int d = o + 4 * lane;
                    const int r = (unsigned)d / 96u;
                    const int c = d - r * 96;
                    const int gr = min(iy0 + r, N_IMG - 1);       // overshoot clamp
                    gload_lds16(img + (size_t)gr * N_IMG + win + c, tile + o);
                }
            } else {
                const float* g = img + (size_t)(iy0 + wv) * N_IMG + win + lane;
                float* l = tile + wv * S;
                for (int r = wv; r < nrows; r += NWAVES) {
                    gload_lds4(g, l);
                    if (dB > 0) gload_lds4(g + dB, l + dB);
                    g += NWAVES * N_IMG;
                    l += NWAVES * S;
                }
            }
        } else {
            // ---- border staging: zero-fill, then guarded float4 copy of the
            //      in-image intersection; samples then use the SAME fast path ----
            for (int o4 = tid; o4 < TILE_WORDS / 4; o4 += NTHREADS)
                *(float4*)(tile + 4 * o4) = make_float4(0.f, 0.f, 0.f, 0.f);
            __syncthreads();
            const int cx0 = max(0, win);                          // 4-aligned
            const int cxe = min(N_IMG - 1, win + 94);             // last needed col
            const int wIn = cxe - cx0 + 1;                        // 1..95
            const int n4  = wIn >> 2;                             // full float4 chunks
            const int items = nrows * 24;
            for (int idx = tid; idx < items; idx += NTHREADS) {
                const int r  = (unsigned)idx / 24u;
                const int c4 = idx - r * 24;
                const int gy = ry0 + r;
                float* dst = tile + (gy - iy0) * S + (cx0 - win) + 4 * c4;
                const float* src = img + (size_t)gy * N_IMG + cx0 + 4 * c4;
                if (c4 < n4) {
                    *(float4*)dst = *(const float4*)src;          // ds_write_b128
                } else if (c4 == n4) {
                    for (int jt = 0; jt < (wIn & 3); ++jt) dst[jt] = src[jt];
                }
            }
        }
        __syncthreads();     // DMA drained + staging visible to all waves

        const float Ybf  = (float)(Yq + j * TILE + wv * YPT);
        const float x_in = fmaf(sa, Ybf, fx0);
        const float y_in = fmaf(ca, Ybf, fy0);
        const float basef = -(float)(iy0 * S + win);
        if (path == 0)      accv += sample_tile<96>(tile, sa, ca, x_in, y_in, basef);
        else if (path == 1) accv += sample_tile<95>(tile, sa, ca, x_in, y_in, basef);
        else                accv += sample_tile<97>(tile, sa, ca, x_in, y_in, basef);

        __syncthreads();     // all waves done reading before next job's staging
    }

    // ---- block reduce (overlay tile) + atomic merge of the 4 y-quarters ----
    tile[wv * 64 + lane] = accv;
    __syncthreads();
    if (wv == 0) {
        float s = 0.0f;
        #pragma unroll
        for (int w = 0; w < NWAVES; ++w) s += tile[w * 64 + lane];
        atomicAdd(&out[(X0 + lane) * N_VIEWS + a], s);
    }
}

extern "C" void kernel_launch(void* const* d_in, const int* in_sizes, int n_in,
                              void* d_out, int out_size, void* d_ws, size_t ws_size,
                              hipStream_t stream) {
    const float* img   = (const float*)d_in[0];   // [1024, 1024] f32
    const float* theta = (const float*)d_in[1];   // [90] f32 degrees
    float* out = (float*)d_out;                   // [1024, 90] f32
    (void)d_ws; (void)ws_size;

    (void)hipMemsetAsync(d_out, 0, (size_t)out_size * sizeof(float), stream);
    radon_fused<<<dim3(16, JOBS == 4 ? 4 : 4, N_VIEWS), NTHREADS, 0, stream>>>(img, theta, out);
}